// Round 1
// baseline (577.345 us; speedup 1.0000x reference)
//
#include <hip/hip_runtime.h>
#include <math.h>

#define N_NODES 50000
#define DIM     128
#define NHEAD   4
#define NCH     16
#define HC      64
#define NE      800000
#define EDIM    64
#define NEG     0.2f

__device__ __forceinline__ float lrelu(float v) { return v > 0.f ? v : NEG * v; }

// ---------------- K1: v_edge[h][d] = sum_c att_edge[h,c] * W_edge[h*16+c, d] ----------------
__global__ void k1_vedge(const float* __restrict__ W_edge, const float* __restrict__ att_edge,
                         float* __restrict__ v_edge) {
    int t = threadIdx.x;          // 256 threads
    int h = t >> 6, d = t & 63;
    float acc = 0.f;
    #pragma unroll
    for (int c = 0; c < NCH; ++c)
        acc = fmaf(att_edge[h * NCH + c], W_edge[(h * NCH + c) * EDIM + d], acc);
    v_edge[h * 64 + d] = acc;
}

// ---------------- K2: xh = x @ W^T  [N,64]; a_src/a_dst [N,4] ----------------
// block 256 threads = 64 row-pairs x 4 heads; 128 rows per block; W transposed in LDS (stride 68).
__global__ __launch_bounds__(256) void k2_xh(const float* __restrict__ x, const float* __restrict__ W,
                                             const float* __restrict__ att_src, const float* __restrict__ att_dst,
                                             float* __restrict__ xh, float* __restrict__ a_src,
                                             float* __restrict__ a_dst) {
    __shared__ float Wt[128 * 68];   // Wt[k*68 + col]
    int t = threadIdx.x;
    for (int idx = t; idx < 64 * 128; idx += 256) {
        int col = idx >> 7, k = idx & 127;
        Wt[k * 68 + col] = W[idx];
    }
    __syncthreads();

    int h  = t & 3;
    int rp = t >> 2;                       // 0..63
    int row0 = blockIdx.x * 128 + rp * 2;  // this thread: rows row0, row0+1, head h
    int r0 = min(row0, N_NODES - 1);
    int r1 = min(row0 + 1, N_NODES - 1);
    const float4* x0 = (const float4*)(x + (size_t)r0 * DIM);
    const float4* x1 = (const float4*)(x + (size_t)r1 * DIM);

    float acc0[16], acc1[16];
    #pragma unroll
    for (int c = 0; c < 16; ++c) { acc0[c] = 0.f; acc1[c] = 0.f; }

    for (int k4 = 0; k4 < 32; ++k4) {
        float4 xa = x0[k4];
        float4 xb = x1[k4];
        #pragma unroll
        for (int kk = 0; kk < 4; ++kk) {
            float va = (&xa.x)[kk];
            float vb = (&xb.x)[kk];
            const float* wr = &Wt[(k4 * 4 + kk) * 68 + h * 16];
            #pragma unroll
            for (int j = 0; j < 4; ++j) {
                float4 w = *(const float4*)(wr + 4 * j);
                acc0[4 * j + 0] = fmaf(va, w.x, acc0[4 * j + 0]);
                acc0[4 * j + 1] = fmaf(va, w.y, acc0[4 * j + 1]);
                acc0[4 * j + 2] = fmaf(va, w.z, acc0[4 * j + 2]);
                acc0[4 * j + 3] = fmaf(va, w.w, acc0[4 * j + 3]);
                acc1[4 * j + 0] = fmaf(vb, w.x, acc1[4 * j + 0]);
                acc1[4 * j + 1] = fmaf(vb, w.y, acc1[4 * j + 1]);
                acc1[4 * j + 2] = fmaf(vb, w.z, acc1[4 * j + 2]);
                acc1[4 * j + 3] = fmaf(vb, w.w, acc1[4 * j + 3]);
            }
        }
    }

    if (row0 < N_NODES) {
        float4* o = (float4*)(xh + (size_t)row0 * HC + h * 16);
        o[0] = make_float4(acc0[0], acc0[1], acc0[2], acc0[3]);
        o[1] = make_float4(acc0[4], acc0[5], acc0[6], acc0[7]);
        o[2] = make_float4(acc0[8], acc0[9], acc0[10], acc0[11]);
        o[3] = make_float4(acc0[12], acc0[13], acc0[14], acc0[15]);
        float ss = 0.f, sd = 0.f;
        #pragma unroll
        for (int c = 0; c < 16; ++c) {
            ss = fmaf(acc0[c], att_src[h * 16 + c], ss);
            sd = fmaf(acc0[c], att_dst[h * 16 + c], sd);
        }
        a_src[row0 * 4 + h] = ss;
        a_dst[row0 * 4 + h] = sd;
    }
    if (row0 + 1 < N_NODES) {
        float4* o = (float4*)(xh + (size_t)(row0 + 1) * HC + h * 16);
        o[0] = make_float4(acc1[0], acc1[1], acc1[2], acc1[3]);
        o[1] = make_float4(acc1[4], acc1[5], acc1[6], acc1[7]);
        o[2] = make_float4(acc1[8], acc1[9], acc1[10], acc1[11]);
        o[3] = make_float4(acc1[12], acc1[13], acc1[14], acc1[15]);
        float ss = 0.f, sd = 0.f;
        #pragma unroll
        for (int c = 0; c < 16; ++c) {
            ss = fmaf(acc1[c], att_src[h * 16 + c], ss);
            sd = fmaf(acc1[c], att_dst[h * 16 + c], sd);
        }
        a_src[(row0 + 1) * 4 + h] = ss;
        a_dst[(row0 + 1) * 4 + h] = sd;
    }
}

// ---------------- K3: per-edge a_e, alpha_pre (lrelu), loop_sum(+=raw a_e), deg count -------
__global__ __launch_bounds__(256) void k3_edge(const float* __restrict__ edge_attr,
                                               const int* __restrict__ ei,
                                               const float* __restrict__ v_edge,
                                               const float* __restrict__ a_src,
                                               const float* __restrict__ a_dst,
                                               float* __restrict__ alpha_pre,
                                               float* __restrict__ loop_sum,
                                               int* __restrict__ deg) {
    __shared__ float4 sv[64];   // v_edge as float4: sv[h*16 + j]
    int t = threadIdx.x;
    if (t < 64) sv[t] = ((const float4*)v_edge)[t];
    __syncthreads();
    int e = blockIdx.x * 256 + t;
    if (e >= NE) return;

    const float4* ea = (const float4*)(edge_attr + (size_t)e * EDIM);
    float p0 = 0.f, p1 = 0.f, p2 = 0.f, p3 = 0.f;
    #pragma unroll
    for (int j = 0; j < 16; ++j) {
        float4 v  = ea[j];
        float4 w0 = sv[j], w1 = sv[16 + j], w2 = sv[32 + j], w3 = sv[48 + j];
        p0 = fmaf(v.x, w0.x, fmaf(v.y, w0.y, fmaf(v.z, w0.z, fmaf(v.w, w0.w, p0))));
        p1 = fmaf(v.x, w1.x, fmaf(v.y, w1.y, fmaf(v.z, w1.z, fmaf(v.w, w1.w, p1))));
        p2 = fmaf(v.x, w2.x, fmaf(v.y, w2.y, fmaf(v.z, w2.z, fmaf(v.w, w2.w, p2))));
        p3 = fmaf(v.x, w3.x, fmaf(v.y, w3.y, fmaf(v.z, w3.z, fmaf(v.w, w3.w, p3))));
    }
    int src = ei[e];
    int dst = ei[NE + e];
    float4 as = *(const float4*)(a_src + (size_t)src * 4);
    float4 ad = *(const float4*)(a_dst + (size_t)dst * 4);
    float4 o;
    o.x = lrelu(as.x + ad.x + p0);
    o.y = lrelu(as.y + ad.y + p1);
    o.z = lrelu(as.z + ad.z + p2);
    o.w = lrelu(as.w + ad.w + p3);
    *(float4*)(alpha_pre + (size_t)e * 4) = o;
    float* ls = loop_sum + (size_t)dst * 4;
    atomicAdd(ls + 0, p0);
    atomicAdd(ls + 1, p1);
    atomicAdd(ls + 2, p2);
    atomicAdd(ls + 3, p3);
    atomicAdd(deg + dst, 1);
}

// ---------------- K4: 3-kernel exclusive scan of deg -> rowptr, cursor ----------------
__global__ void k4a_scan(const int* __restrict__ deg, int* __restrict__ tmp, int* __restrict__ bsums) {
    int t = threadIdx.x;
    int i = blockIdx.x * 256 + t;
    int v = (i < N_NODES) ? deg[i] : 0;
    int lane = t & 63, w = t >> 6;
    int xv = v;
    #pragma unroll
    for (int o = 1; o < 64; o <<= 1) {
        int y = __shfl_up(xv, o);
        if (lane >= o) xv += y;
    }
    __shared__ int wtot[4];
    if (lane == 63) wtot[w] = xv;
    __syncthreads();
    int add = 0;
    #pragma unroll
    for (int j = 0; j < 4; ++j)
        if (j < w) add += wtot[j];
    xv += add;
    if (i < N_NODES) tmp[i] = xv;            // inclusive within block
    if (t == 255) bsums[blockIdx.x] = xv;    // block total
}

__global__ void k4b_scan(int* __restrict__ bsums, int nb) {
    int t = threadIdx.x;
    int v = (t < nb) ? bsums[t] : 0;
    int lane = t & 63, w = t >> 6;
    int xv = v;
    #pragma unroll
    for (int o = 1; o < 64; o <<= 1) {
        int y = __shfl_up(xv, o);
        if (lane >= o) xv += y;
    }
    __shared__ int wtot[4];
    if (lane == 63) wtot[w] = xv;
    __syncthreads();
    int add = 0;
    #pragma unroll
    for (int j = 0; j < 4; ++j)
        if (j < w) add += wtot[j];
    xv += add;
    if (t < nb) bsums[t] = xv - v;           // exclusive block offset
}

__global__ void k4c_finish(const int* __restrict__ tmp, const int* __restrict__ bsums,
                           const int* __restrict__ deg, int* __restrict__ rowptr,
                           int* __restrict__ cursor) {
    int i = blockIdx.x * 256 + threadIdx.x;
    if (i >= N_NODES) return;
    int incl = tmp[i] + bsums[i >> 8];
    rowptr[i + 1] = incl;
    cursor[i] = incl - deg[i];
    if (i == 0) rowptr[0] = 0;
}

// ---------------- K5: scatter edges into CSR order (copy src id + alpha) ----------------
__global__ __launch_bounds__(256) void k5_scatter(const int* __restrict__ ei,
                                                  const float* __restrict__ alpha_pre,
                                                  int* __restrict__ cursor,
                                                  int* __restrict__ csr_src,
                                                  float* __restrict__ csr_alpha) {
    int e = blockIdx.x * 256 + threadIdx.x;
    if (e >= NE) return;
    int src = ei[e];
    int dst = ei[NE + e];
    int pos = atomicAdd(cursor + dst, 1);
    csr_src[pos] = src;
    float4 a = *(const float4*)(alpha_pre + (size_t)e * 4);
    *(float4*)(csr_alpha + (size_t)pos * 4) = a;
}

// ---------------- K6: wave per node — softmax denom + weighted aggregation ----------------
__global__ __launch_bounds__(256) void k6_agg(const int* __restrict__ rowptr,
                                              const int* __restrict__ csr_src,
                                              const float* __restrict__ csr_alpha,
                                              const float* __restrict__ xh,
                                              const float* __restrict__ a_src,
                                              const float* __restrict__ a_dst,
                                              const float* __restrict__ loop_sum,
                                              const float* __restrict__ bias,
                                              float* __restrict__ out) {
    int lane = threadIdx.x & 63;
    int n = blockIdx.x * 4 + (threadIdx.x >> 6);
    if (n >= N_NODES) return;
    int start = rowptr[n], end = rowptr[n + 1];
    int degn = end - start;

    // phase 1: denominators. lane = slot*4 + h
    int h = lane & 3;
    float s = 0.f;
    for (int i = start + (lane >> 2); i < end; i += 16)
        s += __expf(csr_alpha[(size_t)i * 4 + h]);
    s += __shfl_xor(s, 4);
    s += __shfl_xor(s, 8);
    s += __shfl_xor(s, 16);
    s += __shfl_xor(s, 32);

    float al    = loop_sum[n * 4 + h] / fmaxf((float)degn, 1.f);
    float wself = __expf(lrelu(a_src[n * 4 + h] + a_dst[n * 4 + h] + al));
    float denom = s + wself + 1e-16f;

    // phase 2: accumulate. lane = h2*16 + c
    int h2 = lane >> 4;
    float d2  = __shfl(denom, h2);
    float ws2 = __shfl(wself, h2);
    float acc = ws2 * xh[(size_t)n * HC + lane];

    int i = start;
    for (; i + 4 <= end; i += 4) {
        int s0 = csr_src[i], s1 = csr_src[i + 1], s2 = csr_src[i + 2], s3 = csr_src[i + 3];
        float a0 = csr_alpha[(size_t)(i + 0) * 4 + h2];
        float a1 = csr_alpha[(size_t)(i + 1) * 4 + h2];
        float a2 = csr_alpha[(size_t)(i + 2) * 4 + h2];
        float a3 = csr_alpha[(size_t)(i + 3) * 4 + h2];
        float x0 = xh[(size_t)s0 * HC + lane];
        float x1 = xh[(size_t)s1 * HC + lane];
        float x2 = xh[(size_t)s2 * HC + lane];
        float x3 = xh[(size_t)s3 * HC + lane];
        acc = fmaf(__expf(a0), x0, acc);
        acc = fmaf(__expf(a1), x1, acc);
        acc = fmaf(__expf(a2), x2, acc);
        acc = fmaf(__expf(a3), x3, acc);
    }
    for (; i < end; ++i) {
        int sv = csr_src[i];
        float av = csr_alpha[(size_t)i * 4 + h2];
        acc = fmaf(__expf(av), xh[(size_t)sv * HC + lane], acc);
    }
    out[(size_t)n * HC + lane] = acc / d2 + bias[lane];
}

// ---------------- launcher ----------------
extern "C" void kernel_launch(void* const* d_in, const int* in_sizes, int n_in,
                              void* d_out, int out_size, void* d_ws, size_t ws_size,
                              hipStream_t stream) {
    const float* x         = (const float*)d_in[0];
    const int*   ei        = (const int*)d_in[1];
    const float* edge_attr = (const float*)d_in[2];
    const float* W         = (const float*)d_in[3];
    const float* W_edge    = (const float*)d_in[4];
    const float* att_src   = (const float*)d_in[5];
    const float* att_dst   = (const float*)d_in[6];
    const float* att_edge  = (const float*)d_in[7];
    const float* bias      = (const float*)d_in[8];
    float* out = (float*)d_out;

    char* ws = (char*)d_ws;
    size_t off = 0;
    float* v_edge    = (float*)(ws + off); off += 1024;                      // 256 f
    float* xh        = (float*)(ws + off); off += (size_t)N_NODES * HC * 4;  // 12.8 MB
    float* a_src     = (float*)(ws + off); off += (size_t)N_NODES * 4 * 4;
    float* a_dst     = (float*)(ws + off); off += (size_t)N_NODES * 4 * 4;
    float* loop_sum  = (float*)(ws + off); off += (size_t)N_NODES * 4 * 4;
    int*   deg       = (int*)(ws + off);   off += (size_t)N_NODES * 4;
    int*   tmp       = (int*)(ws + off);   off += (size_t)N_NODES * 4;
    int*   bsums     = (int*)(ws + off);   off += 1024;
    int*   rowptr    = (int*)(ws + off);   off += (size_t)(N_NODES + 4) * 4;
    int*   cursor    = (int*)(ws + off);   off += (size_t)N_NODES * 4;
    float* alpha_pre = (float*)(ws + off); off += (size_t)NE * 4 * 4;        // 12.8 MB
    int*   csr_src   = (int*)(ws + off);   off += (size_t)NE * 4;            // 3.2 MB
    float* csr_alpha = (float*)(ws + off); off += (size_t)NE * 4 * 4;        // 12.8 MB

    // zero loop_sum + deg (contiguous)
    hipMemsetAsync(loop_sum, 0, (size_t)N_NODES * 4 * 4 + (size_t)N_NODES * 4, stream);

    k1_vedge<<<1, 256, 0, stream>>>(W_edge, att_edge, v_edge);
    k2_xh<<<(N_NODES + 127) / 128, 256, 0, stream>>>(x, W, att_src, att_dst, xh, a_src, a_dst);
    k3_edge<<<(NE + 255) / 256, 256, 0, stream>>>(edge_attr, ei, v_edge, a_src, a_dst,
                                                  alpha_pre, loop_sum, deg);
    int nb = (N_NODES + 255) / 256;   // 196
    k4a_scan<<<nb, 256, 0, stream>>>(deg, tmp, bsums);
    k4b_scan<<<1, 256, 0, stream>>>(bsums, nb);
    k4c_finish<<<nb, 256, 0, stream>>>(tmp, bsums, deg, rowptr, cursor);
    k5_scatter<<<(NE + 255) / 256, 256, 0, stream>>>(ei, alpha_pre, cursor, csr_src, csr_alpha);
    k6_agg<<<(N_NODES + 3) / 4, 256, 0, stream>>>(rowptr, csr_src, csr_alpha, xh,
                                                  a_src, a_dst, loop_sum, bias, out);
}

// Round 2
// 468.551 us; speedup vs baseline: 1.2322x; 1.2322x over previous
//
#include <hip/hip_runtime.h>
#include <math.h>

#define N_NODES 50000
#define DIM     128
#define NHEAD   4
#define NCH     16
#define HC      64
#define NE      800000
#define EDIM    64
#define NEG     0.2f

__device__ __forceinline__ float lrelu(float v) { return v > 0.f ? v : NEG * v; }

// ---------------- K1: v_edge[h][d] = sum_c att_edge[h,c] * W_edge[h*16+c, d] ----------------
__global__ void k1_vedge(const float* __restrict__ W_edge, const float* __restrict__ att_edge,
                         float* __restrict__ v_edge) {
    int t = threadIdx.x;          // 256 threads
    int h = t >> 6, d = t & 63;
    float acc = 0.f;
    #pragma unroll
    for (int c = 0; c < NCH; ++c)
        acc = fmaf(att_edge[h * NCH + c], W_edge[(h * NCH + c) * EDIM + d], acc);
    v_edge[h * 64 + d] = acc;
}

// ---------------- K2: xh = x @ W^T  [N,64]; a_src/a_dst [N,4] ----------------
__global__ __launch_bounds__(256) void k2_xh(const float* __restrict__ x, const float* __restrict__ W,
                                             const float* __restrict__ att_src, const float* __restrict__ att_dst,
                                             float* __restrict__ xh, float* __restrict__ a_src,
                                             float* __restrict__ a_dst) {
    __shared__ float Wt[128 * 68];   // Wt[k*68 + col]
    int t = threadIdx.x;
    for (int idx = t; idx < 64 * 128; idx += 256) {
        int col = idx >> 7, k = idx & 127;
        Wt[k * 68 + col] = W[idx];
    }
    __syncthreads();

    int h  = t & 3;
    int rp = t >> 2;                       // 0..63
    int row0 = blockIdx.x * 128 + rp * 2;  // this thread: rows row0, row0+1, head h
    int r0 = min(row0, N_NODES - 1);
    int r1 = min(row0 + 1, N_NODES - 1);
    const float4* x0 = (const float4*)(x + (size_t)r0 * DIM);
    const float4* x1 = (const float4*)(x + (size_t)r1 * DIM);

    float acc0[16], acc1[16];
    #pragma unroll
    for (int c = 0; c < 16; ++c) { acc0[c] = 0.f; acc1[c] = 0.f; }

    for (int k4 = 0; k4 < 32; ++k4) {
        float4 xa = x0[k4];
        float4 xb = x1[k4];
        #pragma unroll
        for (int kk = 0; kk < 4; ++kk) {
            float va = (&xa.x)[kk];
            float vb = (&xb.x)[kk];
            const float* wr = &Wt[(k4 * 4 + kk) * 68 + h * 16];
            #pragma unroll
            for (int j = 0; j < 4; ++j) {
                float4 w = *(const float4*)(wr + 4 * j);
                acc0[4 * j + 0] = fmaf(va, w.x, acc0[4 * j + 0]);
                acc0[4 * j + 1] = fmaf(va, w.y, acc0[4 * j + 1]);
                acc0[4 * j + 2] = fmaf(va, w.z, acc0[4 * j + 2]);
                acc0[4 * j + 3] = fmaf(va, w.w, acc0[4 * j + 3]);
                acc1[4 * j + 0] = fmaf(vb, w.x, acc1[4 * j + 0]);
                acc1[4 * j + 1] = fmaf(vb, w.y, acc1[4 * j + 1]);
                acc1[4 * j + 2] = fmaf(vb, w.z, acc1[4 * j + 2]);
                acc1[4 * j + 3] = fmaf(vb, w.w, acc1[4 * j + 3]);
            }
        }
    }

    if (row0 < N_NODES) {
        float4* o = (float4*)(xh + (size_t)row0 * HC + h * 16);
        o[0] = make_float4(acc0[0], acc0[1], acc0[2], acc0[3]);
        o[1] = make_float4(acc0[4], acc0[5], acc0[6], acc0[7]);
        o[2] = make_float4(acc0[8], acc0[9], acc0[10], acc0[11]);
        o[3] = make_float4(acc0[12], acc0[13], acc0[14], acc0[15]);
        float ss = 0.f, sd = 0.f;
        #pragma unroll
        for (int c = 0; c < 16; ++c) {
            ss = fmaf(acc0[c], att_src[h * 16 + c], ss);
            sd = fmaf(acc0[c], att_dst[h * 16 + c], sd);
        }
        a_src[row0 * 4 + h] = ss;
        a_dst[row0 * 4 + h] = sd;
    }
    if (row0 + 1 < N_NODES) {
        float4* o = (float4*)(xh + (size_t)(row0 + 1) * HC + h * 16);
        o[0] = make_float4(acc1[0], acc1[1], acc1[2], acc1[3]);
        o[1] = make_float4(acc1[4], acc1[5], acc1[6], acc1[7]);
        o[2] = make_float4(acc1[8], acc1[9], acc1[10], acc1[11]);
        o[3] = make_float4(acc1[12], acc1[13], acc1[14], acc1[15]);
        float ss = 0.f, sd = 0.f;
        #pragma unroll
        for (int c = 0; c < 16; ++c) {
            ss = fmaf(acc1[c], att_src[h * 16 + c], ss);
            sd = fmaf(acc1[c], att_dst[h * 16 + c], sd);
        }
        a_src[(row0 + 1) * 4 + h] = ss;
        a_dst[(row0 + 1) * 4 + h] = sd;
    }
}

// ---------------- PassA: deg histogram (int atomics only) ----------------
__global__ __launch_bounds__(256) void ka_deg(const int* __restrict__ ei, int* __restrict__ deg) {
    int e = blockIdx.x * 256 + threadIdx.x;
    if (e >= NE) return;
    atomicAdd(deg + ei[NE + e], 1);
}

// ---------------- K4: 3-kernel exclusive scan of deg -> rowptr, cursor ----------------
__global__ void k4a_scan(const int* __restrict__ deg, int* __restrict__ tmp, int* __restrict__ bsums) {
    int t = threadIdx.x;
    int i = blockIdx.x * 256 + t;
    int v = (i < N_NODES) ? deg[i] : 0;
    int lane = t & 63, w = t >> 6;
    int xv = v;
    #pragma unroll
    for (int o = 1; o < 64; o <<= 1) {
        int y = __shfl_up(xv, o);
        if (lane >= o) xv += y;
    }
    __shared__ int wtot[4];
    if (lane == 63) wtot[w] = xv;
    __syncthreads();
    int add = 0;
    #pragma unroll
    for (int j = 0; j < 4; ++j)
        if (j < w) add += wtot[j];
    xv += add;
    if (i < N_NODES) tmp[i] = xv;            // inclusive within block
    if (t == 255) bsums[blockIdx.x] = xv;    // block total
}

__global__ void k4b_scan(int* __restrict__ bsums, int nb) {
    int t = threadIdx.x;
    int v = (t < nb) ? bsums[t] : 0;
    int lane = t & 63, w = t >> 6;
    int xv = v;
    #pragma unroll
    for (int o = 1; o < 64; o <<= 1) {
        int y = __shfl_up(xv, o);
        if (lane >= o) xv += y;
    }
    __shared__ int wtot[4];
    if (lane == 63) wtot[w] = xv;
    __syncthreads();
    int add = 0;
    #pragma unroll
    for (int j = 0; j < 4; ++j)
        if (j < w) add += wtot[j];
    xv += add;
    if (t < nb) bsums[t] = xv - v;           // exclusive block offset
}

__global__ void k4c_finish(const int* __restrict__ tmp, const int* __restrict__ bsums,
                           const int* __restrict__ deg, int* __restrict__ rowptr,
                           int* __restrict__ cursor) {
    int i = blockIdx.x * 256 + threadIdx.x;
    if (i >= N_NODES) return;
    int incl = tmp[i] + bsums[i >> 8];
    rowptr[i + 1] = incl;
    cursor[i] = incl - deg[i];
    if (i == 0) rowptr[0] = 0;
}

// ---------------- PassB (fused K3+K5): stream edge_attr -> p, scatter into CSR ----------------
__global__ __launch_bounds__(256) void kb_edge(const float* __restrict__ edge_attr,
                                               const int* __restrict__ ei,
                                               const float* __restrict__ v_edge,
                                               int* __restrict__ cursor,
                                               int* __restrict__ csr_src,
                                               float* __restrict__ csr_p) {
    __shared__ float4 sv[64];   // v_edge as float4: sv[h*16 + j]
    int t = threadIdx.x;
    if (t < 64) sv[t] = ((const float4*)v_edge)[t];
    __syncthreads();
    int e = blockIdx.x * 256 + t;
    if (e >= NE) return;

    const float4* ea = (const float4*)(edge_attr + (size_t)e * EDIM);
    float p0 = 0.f, p1 = 0.f, p2 = 0.f, p3 = 0.f;
    #pragma unroll
    for (int j = 0; j < 16; ++j) {
        float4 v  = ea[j];
        float4 w0 = sv[j], w1 = sv[16 + j], w2 = sv[32 + j], w3 = sv[48 + j];
        p0 = fmaf(v.x, w0.x, fmaf(v.y, w0.y, fmaf(v.z, w0.z, fmaf(v.w, w0.w, p0))));
        p1 = fmaf(v.x, w1.x, fmaf(v.y, w1.y, fmaf(v.z, w1.z, fmaf(v.w, w1.w, p1))));
        p2 = fmaf(v.x, w2.x, fmaf(v.y, w2.y, fmaf(v.z, w2.z, fmaf(v.w, w2.w, p2))));
        p3 = fmaf(v.x, w3.x, fmaf(v.y, w3.y, fmaf(v.z, w3.z, fmaf(v.w, w3.w, p3))));
    }
    int src = ei[e];
    int dst = ei[NE + e];
    int pos = atomicAdd(cursor + dst, 1);
    csr_src[pos] = src;
    *(float4*)(csr_p + (size_t)pos * 4) = make_float4(p0, p1, p2, p3);
}

// ---------------- K6: wave per node — self-loop mean + softmax denom + aggregation ----------------
__global__ __launch_bounds__(256) void k6_agg(const int* __restrict__ rowptr,
                                              const int* __restrict__ csr_src,
                                              const float* __restrict__ csr_p,
                                              const float* __restrict__ xh,
                                              const float* __restrict__ a_src,
                                              const float* __restrict__ a_dst,
                                              const float* __restrict__ bias,
                                              float* __restrict__ out) {
    int lane = threadIdx.x & 63;
    int n = blockIdx.x * 4 + (threadIdx.x >> 6);
    if (n >= N_NODES) return;
    int start = rowptr[n], end = rowptr[n + 1];
    int degn = end - start;

    // phase 1: per-head exp-weight sum + raw-p sum.  lane = slot*4 + h
    int h = lane & 3;
    float adh = a_dst[n * 4 + h];
    float sw = 0.f, sp = 0.f;
    for (int i = start + (lane >> 2); i < end; i += 16) {
        int s  = csr_src[i];
        float p = csr_p[(size_t)i * 4 + h];
        float a = a_src[(size_t)s * 4 + h];
        sw += __expf(lrelu(a + adh + p));
        sp += p;
    }
    sw += __shfl_xor(sw, 4);  sp += __shfl_xor(sp, 4);
    sw += __shfl_xor(sw, 8);  sp += __shfl_xor(sp, 8);
    sw += __shfl_xor(sw, 16); sp += __shfl_xor(sp, 16);
    sw += __shfl_xor(sw, 32); sp += __shfl_xor(sp, 32);

    float al    = sp / fmaxf((float)degn, 1.f);
    float wself = __expf(lrelu(a_src[n * 4 + h] + adh + al));
    float denom = sw + wself + 1e-16f;

    // phase 2: accumulate. lane = h2*16 + c
    int h2 = lane >> 4;
    float d2   = __shfl(denom, h2);
    float ws2  = __shfl(wself, h2);
    float adh2 = __shfl(adh, h2);
    float acc = ws2 * xh[(size_t)n * HC + lane];

    int i = start;
    for (; i + 4 <= end; i += 4) {
        int s0 = csr_src[i], s1 = csr_src[i + 1], s2 = csr_src[i + 2], s3 = csr_src[i + 3];
        float p0 = csr_p[(size_t)(i + 0) * 4 + h2];
        float p1 = csr_p[(size_t)(i + 1) * 4 + h2];
        float p2 = csr_p[(size_t)(i + 2) * 4 + h2];
        float p3 = csr_p[(size_t)(i + 3) * 4 + h2];
        float w0 = __expf(lrelu(a_src[(size_t)s0 * 4 + h2] + adh2 + p0));
        float w1 = __expf(lrelu(a_src[(size_t)s1 * 4 + h2] + adh2 + p1));
        float w2 = __expf(lrelu(a_src[(size_t)s2 * 4 + h2] + adh2 + p2));
        float w3 = __expf(lrelu(a_src[(size_t)s3 * 4 + h2] + adh2 + p3));
        float x0 = xh[(size_t)s0 * HC + lane];
        float x1 = xh[(size_t)s1 * HC + lane];
        float x2 = xh[(size_t)s2 * HC + lane];
        float x3 = xh[(size_t)s3 * HC + lane];
        acc = fmaf(w0, x0, acc);
        acc = fmaf(w1, x1, acc);
        acc = fmaf(w2, x2, acc);
        acc = fmaf(w3, x3, acc);
    }
    for (; i < end; ++i) {
        int sv = csr_src[i];
        float pv = csr_p[(size_t)i * 4 + h2];
        float wv = __expf(lrelu(a_src[(size_t)sv * 4 + h2] + adh2 + pv));
        acc = fmaf(wv, xh[(size_t)sv * HC + lane], acc);
    }
    out[(size_t)n * HC + lane] = acc / d2 + bias[lane];
}

// ---------------- launcher ----------------
extern "C" void kernel_launch(void* const* d_in, const int* in_sizes, int n_in,
                              void* d_out, int out_size, void* d_ws, size_t ws_size,
                              hipStream_t stream) {
    const float* x         = (const float*)d_in[0];
    const int*   ei        = (const int*)d_in[1];
    const float* edge_attr = (const float*)d_in[2];
    const float* W         = (const float*)d_in[3];
    const float* W_edge    = (const float*)d_in[4];
    const float* att_src   = (const float*)d_in[5];
    const float* att_dst   = (const float*)d_in[6];
    const float* att_edge  = (const float*)d_in[7];
    const float* bias      = (const float*)d_in[8];
    float* out = (float*)d_out;

    char* ws = (char*)d_ws;
    size_t off = 0;
    float* v_edge    = (float*)(ws + off); off += 1024;                      // 256 f
    float* xh        = (float*)(ws + off); off += (size_t)N_NODES * HC * 4;  // 12.8 MB
    float* a_src     = (float*)(ws + off); off += (size_t)N_NODES * 4 * 4;
    float* a_dst     = (float*)(ws + off); off += (size_t)N_NODES * 4 * 4;
    int*   deg       = (int*)(ws + off);   off += (size_t)N_NODES * 4;
    int*   tmp       = (int*)(ws + off);   off += (size_t)N_NODES * 4;
    int*   bsums     = (int*)(ws + off);   off += 1024;
    int*   rowptr    = (int*)(ws + off);   off += (size_t)(N_NODES + 4) * 4;
    int*   cursor    = (int*)(ws + off);   off += (size_t)N_NODES * 4;
    int*   csr_src   = (int*)(ws + off);   off += (size_t)NE * 4;            // 3.2 MB
    float* csr_p     = (float*)(ws + off); off += (size_t)NE * 4 * 4;        // 12.8 MB

    // zero deg only
    hipMemsetAsync(deg, 0, (size_t)N_NODES * 4, stream);

    k1_vedge<<<1, 256, 0, stream>>>(W_edge, att_edge, v_edge);
    k2_xh<<<(N_NODES + 127) / 128, 256, 0, stream>>>(x, W, att_src, att_dst, xh, a_src, a_dst);
    ka_deg<<<(NE + 255) / 256, 256, 0, stream>>>(ei, deg);
    int nb = (N_NODES + 255) / 256;   // 196
    k4a_scan<<<nb, 256, 0, stream>>>(deg, tmp, bsums);
    k4b_scan<<<1, 256, 0, stream>>>(bsums, nb);
    k4c_finish<<<nb, 256, 0, stream>>>(tmp, bsums, deg, rowptr, cursor);
    kb_edge<<<(NE + 255) / 256, 256, 0, stream>>>(edge_attr, ei, v_edge, cursor, csr_src, csr_p);
    k6_agg<<<(N_NODES + 3) / 4, 256, 0, stream>>>(rowptr, csr_src, csr_p, xh,
                                                  a_src, a_dst, bias, out);
}